// Round 1
// baseline (982.373 us; speedup 1.0000x reference)
//
#include <hip/hip_runtime.h>
#include <stdint.h>

// Problem: B=16384, N_AGENTS=32, EMBED=32, HID=64, N_ACT=5, S_DIM=512, O_DIM=256
#define BTOT   16384
#define ROWS_A 524288          // B*N_AGENTS
#define WT_COLS 1120           // 1024 (hw1) + 32 (hb1) + 32 (hwf) + 32 (v1)

// workspace layout (bytes)
#define WT_OFF    0            // bf16 [1120][512]
#define FC1T_OFF  1146880      // bf16 [64][256]
#define BQ_OFF    1179648      // f32  [524288] best_qs
// total required ws: 3,276,800 B

typedef __attribute__((ext_vector_type(8))) short bf8_t;   // 8 x bf16 (4 VGPRs)
typedef __attribute__((ext_vector_type(4))) float f4_t;    // MFMA acc

__device__ __forceinline__ f4_t mfma16(bf8_t a, bf8_t b, f4_t c) {
    return __builtin_amdgcn_mfma_f32_16x16x32_bf16(a, b, c, 0, 0, 0);
}
__device__ __forceinline__ unsigned short f2bf(float f) {   // RNE truncate to bf16
    union { float f; uint32_t u; } x; x.f = f;
    uint32_t r = x.u + 0x7FFFu + ((x.u >> 16) & 1u);
    return (unsigned short)(r >> 16);
}
__device__ __forceinline__ float bf2f(unsigned short h) {
    union { uint32_t u; float f; } x; x.u = ((uint32_t)h) << 16;
    return x.f;
}

// ---------------------------------------------------------------- prep ------
// Transpose+convert weights to bf16, n-major rows of length K (for b128 frags).
__global__ void prep_kernel(const float* __restrict__ fc1_w,   // [256][64]
                            const float* __restrict__ hw1_w,   // [512][1024]
                            const float* __restrict__ hb1_w,   // [512][32]
                            const float* __restrict__ hwf_w,   // [512][32]
                            const float* __restrict__ v1_w,    // [512][32]
                            unsigned short* __restrict__ Wt,   // [1120][512]
                            unsigned short* __restrict__ fc1t) // [64][256]
{
    int tid = blockIdx.x * 256 + threadIdx.x;
    if (tid < 71680) {                       // 1120*512/8
        int e = tid * 8;
        int c = e >> 9, k0 = e & 511;        // Wt row (hypernet col), k offset
        const float* src; int N, sc;
        if (c < 1024)      { src = hw1_w; N = 1024; sc = c; }
        else if (c < 1056) { src = hb1_w; N = 32;   sc = c - 1024; }
        else if (c < 1088) { src = hwf_w; N = 32;   sc = c - 1056; }
        else               { src = v1_w;  N = 32;   sc = c - 1088; }
        union { unsigned short s[8]; uint4 v; } pk;
        #pragma unroll
        for (int j = 0; j < 8; ++j) pk.s[j] = f2bf(src[(size_t)(k0 + j) * N + sc]);
        *(uint4*)(Wt + (size_t)c * 512 + k0) = pk.v;
    } else if (tid < 73728) {                // fc1t: 64*256/8 = 2048 threads
        int e = (tid - 71680) * 8;
        int n = e >> 8, k0 = e & 255;
        union { unsigned short s[8]; uint4 v; } pk;
        #pragma unroll
        for (int j = 0; j < 8; ++j) pk.s[j] = f2bf(fc1_w[(size_t)(k0 + j) * 64 + n]);
        *(uint4*)(fc1t + n * 256 + k0) = pk.v;
    }
}

// ---------------------------------------------------------- agent net -------
// x = relu(obs@fc1_w + b); q = softmax(x@fc2_w + b); write q and max(q).
// 128 rows/block, 4 waves, each wave: 32 rows x 64 cols via 16x16x32 MFMA.
#define A_SB 264   // fc1t LDS row stride (256+8)
#define A_SA 72    // obs chunk LDS row stride (64+8)
__global__ __launch_bounds__(256, 3)
void agent_kernel(const float* __restrict__ obs,              // [524288][256]
                  const unsigned short* __restrict__ fc1t,    // [64][256] bf16
                  const float* __restrict__ fc1_b,            // [64]
                  const float* __restrict__ fc2_w,            // [64][5]
                  const float* __restrict__ fc2_b,            // [5]
                  float* __restrict__ out_q,                  // [524288][5]
                  float* __restrict__ bq)                     // [524288]
{
    __shared__ unsigned short sB[64 * A_SB];    // 33,792 B, resident all kernel
    __shared__ unsigned short sA[128 * A_SA];   // 18,432 B; reused as x[128][66] bf16
    const int t = threadIdx.x;
    const int R0 = blockIdx.x * 128;
    const int w = t >> 6, lane = t & 63;
    const int c0 = lane & 15, quad = lane >> 4;

    // stage full fc1t (64x256) once
    {
        const uint4* src = (const uint4*)fc1t;   // 2048 uint4
        #pragma unroll
        for (int i = 0; i < 8; ++i) {
            int id = t + i * 256;
            int n = id >> 5, off = (id & 31) * 8;
            *(uint4*)(sB + n * A_SB + off) = src[id];
        }
    }

    f4_t acc[2][4];
    #pragma unroll
    for (int mt = 0; mt < 2; ++mt)
        #pragma unroll
        for (int nt = 0; nt < 4; ++nt) acc[mt][nt] = (f4_t){0.f, 0.f, 0.f, 0.f};

    for (int kc = 0; kc < 4; ++kc) {             // K chunks of 64
        __syncthreads();                         // sB staged / prev chunk reads done
        #pragma unroll
        for (int i = 0; i < 8; ++i) {            // stage 128x64 fp32 -> bf16
            int id = t + i * 256;                // 2048 float4
            int row = id >> 4, off = (id & 15) * 4;
            float4 v = *(const float4*)(obs + (size_t)(R0 + row) * 256 + kc * 64 + off);
            ushort4 o; o.x = f2bf(v.x); o.y = f2bf(v.y); o.z = f2bf(v.z); o.w = f2bf(v.w);
            *(ushort4*)(sA + row * A_SA + off) = o;
        }
        __syncthreads();
        #pragma unroll
        for (int ks = 0; ks < 2; ++ks) {
            int kk = ks * 32 + quad * 8;
            bf8_t af[2], bfr[4];
            af[0] = *(const bf8_t*)(sA + (w * 32 + c0) * A_SA + kk);
            af[1] = *(const bf8_t*)(sA + (w * 32 + 16 + c0) * A_SA + kk);
            #pragma unroll
            for (int nt = 0; nt < 4; ++nt)
                bfr[nt] = *(const bf8_t*)(sB + (nt * 16 + c0) * A_SB + kc * 64 + kk);
            #pragma unroll
            for (int mt = 0; mt < 2; ++mt)
                #pragma unroll
                for (int nt = 0; nt < 4; ++nt)
                    acc[mt][nt] = mfma16(af[mt], bfr[nt], acc[mt][nt]);
        }
    }
    __syncthreads();                             // all frag reads done; reuse sA as x
    unsigned short* xs = sA;                     // x bf16 [128][66]
    #pragma unroll
    for (int nt = 0; nt < 4; ++nt) {
        int col = nt * 16 + c0;
        float bias = fc1_b[col];
        #pragma unroll
        for (int mt = 0; mt < 2; ++mt)
            #pragma unroll
            for (int r = 0; r < 4; ++r) {
                int row = w * 32 + mt * 16 + quad * 4 + r;   // C/D: col=lane&15, row=quad*4+reg
                float v = acc[mt][nt][r] + bias;
                xs[row * 66 + col] = f2bf(fmaxf(v, 0.f));
            }
    }
    __syncthreads();
    // fc2 + softmax: 2 threads per row, each covers 32 of 64 hidden units
    {
        int row = t >> 1, half = t & 1;
        float q[5] = {0.f, 0.f, 0.f, 0.f, 0.f};
        #pragma unroll
        for (int i = 0; i < 32; ++i) {
            int h = half * 32 + i;
            float xv = bf2f(xs[row * 66 + h]);
            #pragma unroll
            for (int j = 0; j < 5; ++j) q[j] += xv * fc2_w[h * 5 + j];
        }
        #pragma unroll
        for (int j = 0; j < 5; ++j) q[j] = q[j] + __shfl_xor(q[j], 1) + fc2_b[j];
        float m = q[0];
        #pragma unroll
        for (int j = 1; j < 5; ++j) m = fmaxf(m, q[j]);
        float e[5], s = 0.f;
        #pragma unroll
        for (int j = 0; j < 5; ++j) { e[j] = __expf(q[j] - m); s += e[j]; }
        float inv = 1.f / s;
        if (half == 0) {
            size_t G = (size_t)R0 + row;
            #pragma unroll
            for (int j = 0; j < 5; ++j) out_q[G * 5 + j] = e[j] * inv;
            bq[G] = inv;                         // max prob = exp(0)/s = 1/s
        }
    }
}

// ------------------------------------------------------- hypernet + mix -----
// Fully fused: GEMM [64,512]@[512,1120] per block; per-group acc consumed into
// per-lane y/b1/wf/v registers; butterfly reduce -> q_tot. No H materialized.
#define B_ST 520   // LDS row stride (512+8)
__global__ __launch_bounds__(256, 1)
void mixer_kernel(const float* __restrict__ states,           // [16384][512]
                  const unsigned short* __restrict__ Wt,      // [1120][512] bf16
                  const float* __restrict__ hw1_b,            // [1024]
                  const float* __restrict__ hb1_b,            // [32]
                  const float* __restrict__ hwf_b,            // [32]
                  const float* __restrict__ v1_b,             // [32]
                  const float* __restrict__ v2_w,             // [32]
                  const float* __restrict__ v2_b,             // [1]
                  const float* __restrict__ bq,               // [16384][32]
                  float* __restrict__ qtot)                   // [16384]
{
    extern __shared__ char smem[];
    unsigned short* sA = (unsigned short*)smem;               // [64][520] 66,560 B
    unsigned short* sB = (unsigned short*)(smem + 66560);     // [64][520] 66,560 B
    float* bqs = (float*)(smem + 133120);                     // [64][36]   9,216 B
    const int t = threadIdx.x;
    const int B0 = blockIdx.x * 64;
    const int w = t >> 6, lane = t & 63;
    const int c0 = lane & 15, quad = lane >> 4;

    // stage states tile (64x512 fp32 -> bf16), full K resident
    #pragma unroll
    for (int i = 0; i < 32; ++i) {
        int id = t + i * 256;                   // 8192 float4
        int row = id >> 7, off = (id & 127) * 4;
        float4 v = *(const float4*)(states + (size_t)(B0 + row) * 512 + off);
        ushort4 o; o.x = f2bf(v.x); o.y = f2bf(v.y); o.z = f2bf(v.z); o.w = f2bf(v.w);
        *(ushort4*)(sA + row * B_ST + off) = o;
    }
    // stage best_qs tile (64x32), stride 36 to break bank conflicts
    #pragma unroll
    for (int i = 0; i < 2; ++i) {
        int id = t + i * 256;                   // 512 float4
        int row = id >> 3, off = (id & 7) * 4;
        float4 v = *(const float4*)(bq + (size_t)(B0 + row) * 32 + off);
        *(float4*)(bqs + row * 36 + off) = v;
    }

    float y_acc[4][2] = {{0.f,0.f},{0.f,0.f},{0.f,0.f},{0.f,0.f}};
    float b1v[4][2], wfv[4][2], vhv[4][2];

    for (int g = 0; g < 18; ++g) {               // 16 agent groups + hb1/hwf + v1
        __syncthreads();                         // staging done / prior reads done
        int nrows = (g == 17) ? 32 : 64;
        int n0 = g * 64;
        int nv4 = nrows * 64;
        for (int id = t; id < nv4; id += 256) {
            int n = id >> 6, off = (id & 63) * 8;
            *(uint4*)(sB + n * B_ST + off) = *(const uint4*)(Wt + (size_t)(n0 + n) * 512 + off);
        }
        __syncthreads();
        int NT = (g == 17) ? 2 : 4;
        f4_t acc[4];
        #pragma unroll
        for (int nt = 0; nt < 4; ++nt) acc[nt] = (f4_t){0.f, 0.f, 0.f, 0.f};
        for (int ks = 0; ks < 16; ++ks) {
            int kk = ks * 32 + quad * 8;
            bf8_t af = *(const bf8_t*)(sA + (w * 16 + c0) * B_ST + kk);
            for (int nt = 0; nt < NT; ++nt) {
                bf8_t bfr = *(const bf8_t*)(sB + (nt * 16 + c0) * B_ST + kk);
                acc[nt] = mfma16(af, bfr, acc[nt]);
            }
        }
        if (g < 16) {                            // w1 cols: agent=col>>5, e=col&31
            #pragma unroll
            for (int nt = 0; nt < 4; ++nt) {
                int colg = n0 + nt * 16 + c0;
                int agent = colg >> 5;
                int eh = nt & 1;                 // e = eh*16 + c0
                float bias = hw1_b[colg];
                #pragma unroll
                for (int r = 0; r < 4; ++r) {
                    int rowl = w * 16 + quad * 4 + r;
                    float w1v = fabsf(acc[nt][r] + bias);
                    y_acc[r][eh] += bqs[rowl * 36 + agent] * w1v;
                }
            }
        } else if (g == 16) {                    // nt 0,1: b1; nt 2,3: wf
            #pragma unroll
            for (int nt = 0; nt < 2; ++nt) {
                float bias = hb1_b[nt * 16 + c0];
                #pragma unroll
                for (int r = 0; r < 4; ++r) b1v[r][nt] = acc[nt][r] + bias;
            }
            #pragma unroll
            for (int nt = 2; nt < 4; ++nt) {
                float bias = hwf_b[(nt - 2) * 16 + c0];
                #pragma unroll
                for (int r = 0; r < 4; ++r) wfv[r][nt - 2] = fabsf(acc[nt][r] + bias);
            }
        } else {                                 // v1 head
            #pragma unroll
            for (int nt = 0; nt < 2; ++nt) {
                float bias = v1_b[nt * 16 + c0];
                #pragma unroll
                for (int r = 0; r < 4; ++r) vhv[r][nt] = fmaxf(acc[nt][r] + bias, 0.f);
            }
        }
    }
    // final per-row math + 16-lane reduction over e
    float v2w0 = v2_w[c0], v2w1 = v2_w[16 + c0], v2b = v2_b[0];
    float p[4];
    #pragma unroll
    for (int r = 0; r < 4; ++r) {
        float y0 = fmaxf(y_acc[r][0] + b1v[r][0], 0.f);
        float y1 = fmaxf(y_acc[r][1] + b1v[r][1], 0.f);
        p[r] = y0 * wfv[r][0] + y1 * wfv[r][1] + vhv[r][0] * v2w0 + vhv[r][1] * v2w1;
    }
    #pragma unroll
    for (int off = 1; off < 16; off <<= 1)
        #pragma unroll
        for (int r = 0; r < 4; ++r) p[r] += __shfl_xor(p[r], off);
    if (c0 == 0) {
        #pragma unroll
        for (int r = 0; r < 4; ++r)
            qtot[B0 + w * 16 + quad * 4 + r] = p[r] + v2b;
    }
}

// ---------------------------------------------------------------- launch ----
extern "C" void kernel_launch(void* const* d_in, const int* in_sizes, int n_in,
                              void* d_out, int out_size, void* d_ws, size_t ws_size,
                              hipStream_t stream) {
    const float* states = (const float*)d_in[0];
    const float* obs    = (const float*)d_in[1];
    const float* fc1_w  = (const float*)d_in[2];
    const float* fc1_b  = (const float*)d_in[3];
    const float* fc2_w  = (const float*)d_in[4];
    const float* fc2_b  = (const float*)d_in[5];
    const float* hw1_w  = (const float*)d_in[6];
    const float* hw1_b  = (const float*)d_in[7];
    const float* hb1_w  = (const float*)d_in[8];
    const float* hb1_b  = (const float*)d_in[9];
    const float* hwf_w  = (const float*)d_in[10];
    const float* hwf_b  = (const float*)d_in[11];
    const float* v1_w   = (const float*)d_in[12];
    const float* v1_b   = (const float*)d_in[13];
    const float* v2_w   = (const float*)d_in[14];
    const float* v2_b   = (const float*)d_in[15];

    unsigned short* Wt   = (unsigned short*)((char*)d_ws + WT_OFF);
    unsigned short* fc1t = (unsigned short*)((char*)d_ws + FC1T_OFF);
    float*          bq   = (float*)((char*)d_ws + BQ_OFF);

    float* out_q = (float*)d_out;                    // agents_qs [524288][5]
    float* qtot  = out_q + (size_t)ROWS_A * 5;       // q_tot [16384]

    prep_kernel<<<288, 256, 0, stream>>>(fc1_w, hw1_w, hb1_w, hwf_w, v1_w, Wt, fc1t);
    agent_kernel<<<ROWS_A / 128, 256, 0, stream>>>(obs, fc1t, fc1_b, fc2_w, fc2_b, out_q, bq);
    (void)hipFuncSetAttribute((const void*)mixer_kernel,
                              hipFuncAttributeMaxDynamicSharedMemorySize, 142336);
    mixer_kernel<<<BTOT / 64, 256, 142336, stream>>>(states, Wt, hw1_b, hb1_b, hwf_b,
                                                     v1_b, v2_w, v2_b, bq, qtot);
}

// Round 2
// 913.818 us; speedup vs baseline: 1.0750x; 1.0750x over previous
//
#include <hip/hip_runtime.h>
#include <stdint.h>

// Problem: B=16384, N_AGENTS=32, EMBED=32, HID=64, N_ACT=5, S_DIM=512, O_DIM=256
#define BTOT   16384
#define ROWS_A 524288          // B*N_AGENTS

// workspace layout (bytes)
#define WT_OFF    0            // bf16 [1152][512]  (1120 real cols + 32 zero pad)
#define FC1T_OFF  1179648      // bf16 [64][256]
#define BQ_OFF    1212416      // f32  [524288] best_qs
// total required ws: 3,309,568 B

typedef __attribute__((ext_vector_type(8))) short bf8_t;   // 8 x bf16 (4 VGPRs)
typedef __attribute__((ext_vector_type(4))) float f4_t;    // MFMA acc

__device__ __forceinline__ f4_t mfma16(bf8_t a, bf8_t b, f4_t c) {
    return __builtin_amdgcn_mfma_f32_16x16x32_bf16(a, b, c, 0, 0, 0);
}
__device__ __forceinline__ unsigned short f2bf(float f) {   // RNE to bf16
    union { float f; uint32_t u; } x; x.f = f;
    uint32_t r = x.u + 0x7FFFu + ((x.u >> 16) & 1u);
    return (unsigned short)(r >> 16);
}
__device__ __forceinline__ bf8_t cvt8(float4 a, float4 b) { // 8 fp32 -> bf8 frag
    union { unsigned short s[8]; bf8_t v; } u;
    u.s[0] = f2bf(a.x); u.s[1] = f2bf(a.y); u.s[2] = f2bf(a.z); u.s[3] = f2bf(a.w);
    u.s[4] = f2bf(b.x); u.s[5] = f2bf(b.y); u.s[6] = f2bf(b.z); u.s[7] = f2bf(b.w);
    return u.v;
}

// ---------------------------------------------------------------- prep ------
// Transpose+convert weights to bf16 n-major [col][k]; Wt zero-padded to 1152
// cols so the mixer's group loop is uniform (compile-time NT=4, full unroll).
__global__ void prep_kernel(const float* __restrict__ fc1_w,   // [256][64]
                            const float* __restrict__ hw1_w,   // [512][1024]
                            const float* __restrict__ hb1_w,   // [512][32]
                            const float* __restrict__ hwf_w,   // [512][32]
                            const float* __restrict__ v1_w,    // [512][32]
                            unsigned short* __restrict__ Wt,   // [1152][512]
                            unsigned short* __restrict__ fc1t) // [64][256]
{
    int tid = blockIdx.x * 256 + threadIdx.x;
    if (tid < 73728) {                       // 1152*512/8
        int c = tid >> 6;                    // Wt row (hypernet col)
        int k0 = (tid & 63) * 8;             // k offset
        union { unsigned short s[8]; uint4 v; } pk;
        if (c < 1120) {
            const float* src; int N, sc;
            if (c < 1024)      { src = hw1_w; N = 1024; sc = c; }
            else if (c < 1056) { src = hb1_w; N = 32;   sc = c - 1024; }
            else if (c < 1088) { src = hwf_w; N = 32;   sc = c - 1056; }
            else               { src = v1_w;  N = 32;   sc = c - 1088; }
            #pragma unroll
            for (int j = 0; j < 8; ++j) pk.s[j] = f2bf(src[(size_t)(k0 + j) * N + sc]);
        } else {
            pk.v = (uint4){0u, 0u, 0u, 0u};  // zero pad cols 1120..1151
        }
        *(uint4*)(Wt + (size_t)c * 512 + k0) = pk.v;
    } else if (tid < 75776) {                // fc1t: 64*256/8 = 2048 threads
        int e = (tid - 73728) * 8;
        int n = e >> 8, k0 = e & 255;
        union { unsigned short s[8]; uint4 v; } pk;
        #pragma unroll
        for (int j = 0; j < 8; ++j) pk.s[j] = f2bf(fc1_w[(size_t)(k0 + j) * 64 + n]);
        *(uint4*)(fc1t + n * 256 + k0) = pk.v;
    }
}

// ---------------------------------------------------------- agent net -------
// A direct global->register (A-frag k-values are 8 contiguous floats), B (fc1t)
// LDS-resident; one sync per block total; epilogue fully in registers via
// 16-lane butterfly. Wave = 16 rows; 4 tiles/wave; block = 64 rows x 4 tiles.
#define A_SB 264   // fc1t LDS row stride (256+8 shorts -> 4-bank row shift)
__global__ __launch_bounds__(256, 4)
void agent_kernel(const float* __restrict__ obs,              // [524288][256]
                  const unsigned short* __restrict__ fc1t,    // [64][256] bf16
                  const float* __restrict__ fc1_b,            // [64]
                  const float* __restrict__ fc2_w,            // [64][5]
                  const float* __restrict__ fc2_b,            // [5]
                  float* __restrict__ out_q,                  // [524288][5]
                  float* __restrict__ bq)                     // [524288]
{
    __shared__ unsigned short sB[64 * A_SB];    // 33,792 B
    const int t = threadIdx.x;
    const int w = t >> 6, lane = t & 63;
    const int c0 = lane & 15, quad = lane >> 4;

    // stage fc1t (64x256 bf16) once
    {
        const uint4* src = (const uint4*)fc1t;   // 2048 uint4
        #pragma unroll
        for (int i = 0; i < 8; ++i) {
            int id = t + i * 256;
            int n = id >> 5, off = (id & 31) * 8;
            *(uint4*)(sB + n * A_SB + off) = src[id];
        }
    }
    // per-lane constants (L1-cached broadcasts)
    float b1c[4], w2l[4][5], b2[5];
    #pragma unroll
    for (int nt = 0; nt < 4; ++nt) {
        int h = nt * 16 + c0;
        b1c[nt] = fc1_b[h];
        #pragma unroll
        for (int j = 0; j < 5; ++j) w2l[nt][j] = fc2_w[h * 5 + j];
    }
    #pragma unroll
    for (int j = 0; j < 5; ++j) b2[j] = fc2_b[j];
    __syncthreads();                             // sB ready; no more barriers

    #pragma unroll 1
    for (int it = 0; it < 4; ++it) {
        size_t rbase = (size_t)blockIdx.x * 256 + it * 64 + w * 16;
        const float* arow = obs + (rbase + c0) * 256;

        f4_t acc[4];
        #pragma unroll
        for (int nt = 0; nt < 4; ++nt) acc[nt] = (f4_t){0.f, 0.f, 0.f, 0.f};

        #pragma unroll
        for (int ks = 0; ks < 8; ++ks) {         // K=256, 32/MFMA
            int kk = ks * 32 + quad * 8;
            float4 a0 = *(const float4*)(arow + kk);
            float4 a1 = *(const float4*)(arow + kk + 4);
            bf8_t af = cvt8(a0, a1);
            #pragma unroll
            for (int nt = 0; nt < 4; ++nt) {
                bf8_t bfr = *(const bf8_t*)(sB + (nt * 16 + c0) * A_SB + kk);
                acc[nt] = mfma16(af, bfr, acc[nt]);
            }
        }
        // relu + fc2 partials: lane holds hid cols {c0,16+c0,32+c0,48+c0} for
        // rows quad*4+r (C/D: col=lane&15, row=quad*4+reg)
        float p[4][5];
        #pragma unroll
        for (int r = 0; r < 4; ++r)
            #pragma unroll
            for (int j = 0; j < 5; ++j) p[r][j] = 0.f;
        #pragma unroll
        for (int nt = 0; nt < 4; ++nt)
            #pragma unroll
            for (int r = 0; r < 4; ++r) {
                float x = fmaxf(acc[nt][r] + b1c[nt], 0.f);
                #pragma unroll
                for (int j = 0; j < 5; ++j) p[r][j] += x * w2l[nt][j];
            }
        // butterfly over the 16 c0-lanes of this quad
        #pragma unroll
        for (int off = 1; off < 16; off <<= 1)
            #pragma unroll
            for (int r = 0; r < 4; ++r)
                #pragma unroll
                for (int j = 0; j < 5; ++j) p[r][j] += __shfl_xor(p[r][j], off);
        // lane c0 (<4) finishes row quad*4+c0
        float q[5];
        #pragma unroll
        for (int j = 0; j < 5; ++j) {
            float v = p[3][j];
            v = (c0 == 2) ? p[2][j] : v;
            v = (c0 == 1) ? p[1][j] : v;
            v = (c0 == 0) ? p[0][j] : v;
            q[j] = v + b2[j];
        }
        float m = q[0];
        #pragma unroll
        for (int j = 1; j < 5; ++j) m = fmaxf(m, q[j]);
        float e[5], s = 0.f;
        #pragma unroll
        for (int j = 0; j < 5; ++j) { e[j] = __expf(q[j] - m); s += e[j]; }
        float inv = 1.f / s;
        if (c0 < 4) {
            size_t G = rbase + quad * 4 + c0;
            #pragma unroll
            for (int j = 0; j < 5; ++j) out_q[G * 5 + j] = e[j] * inv;
            bq[G] = inv;                         // max prob = exp(0)/s = 1/s
        }
    }
}

// ------------------------------------------------------- hypernet + mix -----
// A (states rows, bf16 frags) resident in registers across all 18 groups; only
// sB (one 64-col Wt group) + bqs in LDS -> 2 blocks/CU. All loops full-unroll.
#define M_SB 520   // Wt group LDS row stride (512+8 shorts)
__global__ __launch_bounds__(256, 2)
void mixer_kernel(const float* __restrict__ states,           // [16384][512]
                  const unsigned short* __restrict__ Wt,      // [1152][512] bf16
                  const float* __restrict__ hw1_b,            // [1024]
                  const float* __restrict__ hb1_b,            // [32]
                  const float* __restrict__ hwf_b,            // [32]
                  const float* __restrict__ v1_b,             // [32]
                  const float* __restrict__ v2_w,             // [32]
                  const float* __restrict__ v2_b,             // [1]
                  const float* __restrict__ bq,               // [16384][32]
                  float* __restrict__ qtot)                   // [16384]
{
    extern __shared__ char smem[];
    unsigned short* sB = (unsigned short*)smem;               // [64][520] 66,560 B
    float* bqs = (float*)(smem + 66560);                      // [64][36]   9,216 B
    const int t = threadIdx.x;
    const int B0 = blockIdx.x * 64;
    const int w = t >> 6, lane = t & 63;
    const int c0 = lane & 15, quad = lane >> 4;

    // stage best_qs tile (64x32), stride 36 to break bank conflicts
    #pragma unroll
    for (int i = 0; i < 2; ++i) {
        int id = t + i * 256;                   // 512 float4
        int row = id >> 3, off = (id & 7) * 4;
        *(float4*)(bqs + row * 36 + off) = *(const float4*)(bq + (size_t)(B0 + row) * 32 + off);
    }
    // A: this lane's states row -> 16 bf16 fragments (64 VGPRs), read once
    const float* srow = states + (size_t)(B0 + w * 16 + c0) * 512;
    bf8_t areg[16];
    #pragma unroll
    for (int ks = 0; ks < 16; ++ks) {
        int kk = ks * 32 + quad * 8;
        float4 a0 = *(const float4*)(srow + kk);
        float4 a1 = *(const float4*)(srow + kk + 4);
        areg[ks] = cvt8(a0, a1);
    }

    float y_acc[4][2] = {{0.f,0.f},{0.f,0.f},{0.f,0.f},{0.f,0.f}};
    float b1v[4][2], wfv[4][2], vhv[4][2];

    #pragma unroll 1
    for (int g = 0; g < 18; ++g) {               // 16 agent groups + hb1/hwf + v1(+pad)
        __syncthreads();                         // bqs staged / prior sB reads done
        #pragma unroll
        for (int i = 0; i < 16; ++i) {           // stage 64x512 bf16 group
            int id = t + i * 256;                // 4096 uint4
            int n = id >> 6, off = (id & 63) * 8;
            *(uint4*)(sB + n * M_SB + off) = *(const uint4*)(Wt + (size_t)(g * 64 + n) * 512 + off);
        }
        __syncthreads();
        f4_t acc[4];
        #pragma unroll
        for (int nt = 0; nt < 4; ++nt) acc[nt] = (f4_t){0.f, 0.f, 0.f, 0.f};
        #pragma unroll
        for (int ks = 0; ks < 16; ++ks) {
            int kk = ks * 32 + quad * 8;
            #pragma unroll
            for (int nt = 0; nt < 4; ++nt) {
                bf8_t bfr = *(const bf8_t*)(sB + (nt * 16 + c0) * M_SB + kk);
                acc[nt] = mfma16(areg[ks], bfr, acc[nt]);
            }
        }
        if (g < 16) {                            // w1 cols: agent=col>>5, e=col&31
            #pragma unroll
            for (int nt = 0; nt < 4; ++nt) {
                int colg = g * 64 + nt * 16 + c0;
                int agent = colg >> 5;
                int eh = nt & 1;                 // e = eh*16 + c0
                float bias = hw1_b[colg];
                #pragma unroll
                for (int r = 0; r < 4; ++r) {
                    int rowl = w * 16 + quad * 4 + r;
                    float w1v = fabsf(acc[nt][r] + bias);
                    y_acc[r][eh] += bqs[rowl * 36 + agent] * w1v;
                }
            }
        } else if (g == 16) {                    // nt 0,1: b1; nt 2,3: wf
            #pragma unroll
            for (int nt = 0; nt < 2; ++nt) {
                float bias = hb1_b[nt * 16 + c0];
                #pragma unroll
                for (int r = 0; r < 4; ++r) b1v[r][nt] = acc[nt][r] + bias;
            }
            #pragma unroll
            for (int nt = 2; nt < 4; ++nt) {
                float bias = hwf_b[(nt - 2) * 16 + c0];
                #pragma unroll
                for (int r = 0; r < 4; ++r) wfv[r][nt - 2] = fabsf(acc[nt][r] + bias);
            }
        } else {                                 // v1 head (nt 0,1); nt 2,3 = zero pad
            #pragma unroll
            for (int nt = 0; nt < 2; ++nt) {
                float bias = v1_b[nt * 16 + c0];
                #pragma unroll
                for (int r = 0; r < 4; ++r) vhv[r][nt] = fmaxf(acc[nt][r] + bias, 0.f);
            }
        }
    }
    // final per-row math + 16-lane reduction over e
    float v2w0 = v2_w[c0], v2w1 = v2_w[16 + c0], v2b = v2_b[0];
    float p[4];
    #pragma unroll
    for (int r = 0; r < 4; ++r) {
        float y0 = fmaxf(y_acc[r][0] + b1v[r][0], 0.f);
        float y1 = fmaxf(y_acc[r][1] + b1v[r][1], 0.f);
        p[r] = y0 * wfv[r][0] + y1 * wfv[r][1] + vhv[r][0] * v2w0 + vhv[r][1] * v2w1;
    }
    #pragma unroll
    for (int off = 1; off < 16; off <<= 1)
        #pragma unroll
        for (int r = 0; r < 4; ++r) p[r] += __shfl_xor(p[r], off);
    if (c0 == 0) {
        #pragma unroll
        for (int r = 0; r < 4; ++r)
            qtot[B0 + w * 16 + quad * 4 + r] = p[r] + v2b;
    }
}

// ---------------------------------------------------------------- launch ----
extern "C" void kernel_launch(void* const* d_in, const int* in_sizes, int n_in,
                              void* d_out, int out_size, void* d_ws, size_t ws_size,
                              hipStream_t stream) {
    const float* states = (const float*)d_in[0];
    const float* obs    = (const float*)d_in[1];
    const float* fc1_w  = (const float*)d_in[2];
    const float* fc1_b  = (const float*)d_in[3];
    const float* fc2_w  = (const float*)d_in[4];
    const float* fc2_b  = (const float*)d_in[5];
    const float* hw1_b  = (const float*)d_in[7];
    const float* hb1_w  = (const float*)d_in[8];
    const float* hb1_b  = (const float*)d_in[9];
    const float* hwf_w  = (const float*)d_in[10];
    const float* hwf_b  = (const float*)d_in[11];
    const float* v1_w   = (const float*)d_in[12];
    const float* v1_b   = (const float*)d_in[13];
    const float* v2_w   = (const float*)d_in[14];
    const float* v2_b   = (const float*)d_in[15];
    const float* hw1_w  = (const float*)d_in[6];

    unsigned short* Wt   = (unsigned short*)((char*)d_ws + WT_OFF);
    unsigned short* fc1t = (unsigned short*)((char*)d_ws + FC1T_OFF);
    float*          bq   = (float*)((char*)d_ws + BQ_OFF);

    float* out_q = (float*)d_out;                    // agents_qs [524288][5]
    float* qtot  = out_q + (size_t)ROWS_A * 5;       // q_tot [16384]

    prep_kernel<<<296, 256, 0, stream>>>(fc1_w, hw1_w, hb1_w, hwf_w, v1_w, Wt, fc1t);
    agent_kernel<<<ROWS_A / 256, 256, 0, stream>>>(obs, fc1t, fc1_b, fc2_w, fc2_b, out_q, bq);
    (void)hipFuncSetAttribute((const void*)mixer_kernel,
                              hipFuncAttributeMaxDynamicSharedMemorySize, 75776);
    mixer_kernel<<<BTOT / 64, 256, 75776, stream>>>(states, Wt, hw1_b, hb1_b, hwf_b,
                                                    v1_b, v2_w, v2_b, bq, qtot);
}